// Round 4
// baseline (357.602 us; speedup 1.0000x reference)
//
#include <hip/hip_runtime.h>
#include <cfloat>

#define NEG_BIG (-1e4f)

constexpr int D = 768;
constexpr int S = 12;

// problem sizes
constexpr int Lq = 256, Lp = 512, Wq = 200, Wp = 400;
constexpr int Mq = 16, Mp = 16, Mn = 112;   // Mn = B*N

// workspace layout (float offsets)
constexpr int OFF_WSUM_Q = 0;                       // 16*200*12  = 38400
constexpr int OFF_WSUM_P = 38400;                   // 16*400*12  = 76800
constexpr int OFF_WSUM_N = 115200;                  // 112*400*12 = 537600
constexpr int OFF_CNT_Q  = 652800;                  // 3200
constexpr int OFF_CNT_P  = 656000;                  // 6400
constexpr int OFF_CNT_N  = 662400;                  // 44800
constexpr int OFF_IMP_Q  = 707200;                  // 3200
constexpr int OFF_IMP_P  = 710400;                  // 6400
constexpr int OFF_IMP_N  = 716800;                  // 44800
constexpr int OFF_COEF   = 761600;                  // 144*512 = 73728 -> 835328 total
constexpr int WS_ZERO_FLOATS = 707200;              // wsum + cnt regions

// output layout (float offsets, reference return order)
constexpr int OUT_QP = 0;        // 16*768
constexpr int OUT_PP = 12288;    // 16*768
constexpr int OUT_QL = 24576;    // 16*200*12
constexpr int OUT_PL = 62976;    // 16*400*12
constexpr int OUT_NP = 139776;   // 112*768 -> 225792 total

// ---------------------------------------------------------------------------
// Kernel 1: per-token projection + segment accumulation.
// 192 threads = 3 waves; wave wv owns dim slice [256*wv, 256*wv+256),
// lane owns 4 dims -> weight cache = 48 VGPRs (register-resident).
// Each wave reduces its 12 partials across 64 lanes (14-swizzle
// redistribution) and atomically adds its slice-partial; the three waves'
// atomics merge in L2. One cnt atomic per token (wave 0).
// ---------------------------------------------------------------------------
__global__ __launch_bounds__(192) void k_proj_accum(
    const float* __restrict__ q_h, const float* __restrict__ p_h,
    const float* __restrict__ n_h, const int* __restrict__ q_ids,
    const int* __restrict__ p_ids, const int* __restrict__ n_ids,
    const float* __restrict__ pw, float* __restrict__ ws)
{
    const int bx   = blockIdx.x;
    const int lane = threadIdx.x & 63;
    const int wv   = threadIdx.x >> 6;   // wave id 0..2 = dim slice

    const float* h; const int* ids; float* wsum; float* cnt;
    int L, W, m, t0;
    if (bx < 128)      { h = q_h; ids = q_ids; wsum = ws + OFF_WSUM_Q; cnt = ws + OFF_CNT_Q;
                         L = Lq; W = Wq; m = bx >> 3;  t0 = (bx & 7) * 32; }
    else if (bx < 384) { int r = bx - 128;
                         h = p_h; ids = p_ids; wsum = ws + OFF_WSUM_P; cnt = ws + OFF_CNT_P;
                         L = Lp; W = Wp; m = r >> 4;  t0 = (r & 15) * 32; }
    else               { int r = bx - 384;
                         h = n_h; ids = n_ids; wsum = ws + OFF_WSUM_N; cnt = ws + OFF_CNT_N;
                         L = Lp; W = Wp; m = r >> 4;  t0 = (r & 15) * 32; }

    // register cache of proj_w for this lane's 4 dims (48 floats = 12 float4)
    const int d0 = 256 * wv + 4 * lane;
    float wreg[4][S];
    {
        const float4* base = (const float4*)(pw + (size_t)d0 * S);
#pragma unroll
        for (int q = 0; q < 12; ++q) {
            float4 v = base[q];
            float tmp[4] = {v.x, v.y, v.z, v.w};
#pragma unroll
            for (int c = 0; c < 4; ++c) {
                const int li = 4 * q + c;
                wreg[li / 12][li % 12] = tmp[c];
            }
        }
    }

    const float* hbase = h + (size_t)m * L * D + d0;
    const int*   idrow = ids + m * L;

    const bool b5 = lane & 32, b4 = lane & 16, b3 = lane & 8, b2 = lane & 4;
    const int  off_s = b3 ? 2 : (b2 ? 1 : 0);
    const int  s_fin = (b5 ? 6 : 0) + (b4 ? 3 : 0) + off_s;
    const bool do_at = ((lane & 3) == 0) && !(b3 && b2);

#pragma unroll 4
    for (int t = t0; t < t0 + 32; ++t) {
        const int id = idrow[t];
        const float4 hv = *(const float4*)(hbase + (size_t)t * D);

        float p[S];
        {
            const float hj[4] = {hv.x, hv.y, hv.z, hv.w};
#pragma unroll
            for (int s = 0; s < S; ++s) p[s] = hj[0] * wreg[0][s];
#pragma unroll
            for (int j = 1; j < 4; ++j)
#pragma unroll
                for (int s = 0; s < S; ++s)
                    p[s] = fmaf(hj[j], wreg[j][s], p[s]);
        }

        // ---- redistribution reduce: 12 vals over 64 lanes, 14 swizzles ----
        float a[6];
#pragma unroll
        for (int i = 0; i < 6; ++i) {
            float snd = b5 ? p[i] : p[6 + i];
            float kp  = b5 ? p[6 + i] : p[i];
            a[i] = kp + __shfl_xor(snd, 32, 64);
        }
        float b[3];
#pragma unroll
        for (int i = 0; i < 3; ++i) {
            float snd = b4 ? a[i] : a[3 + i];
            float kp  = b4 ? a[3 + i] : a[i];
            b[i] = kp + __shfl_xor(snd, 16, 64);
        }
        float c0, c1;
        {
            float snd0 = b3 ? b[0] : b[2];
            float kp0  = b3 ? b[2] : b[0];
            c0 = kp0 + __shfl_xor(snd0, 8, 64);
            float snd1 = b3 ? b[1] : 0.f;
            float kp1  = b3 ? 0.f  : b[1];
            c1 = kp1 + __shfl_xor(snd1, 8, 64);
        }
        float snd = b3 ? c0 : (b2 ? c0 : c1);
        float kp  = b3 ? c0 : (b2 ? c1 : c0);
        float d   = kp + __shfl_xor(snd, 4, 64);
        d += __shfl_xor(d, 2, 64);
        d += __shfl_xor(d, 1, 64);

        float* wb = wsum + ((size_t)m * W + id) * S;
        if (do_at)                atomicAdd(wb + s_fin, d);
        if (wv == 0 && lane == 1) atomicAdd(cnt + (size_t)m * W + id, 1.0f);
    }
}

// ---------------------------------------------------------------------------
// Kernel 2: per-word mean + bias, mask, softmax over S, importance.
// ---------------------------------------------------------------------------
__global__ void k_finalize(
    const float* __restrict__ ws_c, float* __restrict__ ws_mut,
    const float* __restrict__ pb, const float* __restrict__ simp,
    float* __restrict__ out)
{
    const int idx = blockIdx.x * blockDim.x + threadIdx.x;
    if (idx >= Mq * Wq + Mp * Wp + Mn * Wp) return;

    const float* wsum; float c; float* imp; float* lgout;
    if (idx < Mq * Wq) {
        wsum = ws_c + OFF_WSUM_Q + (size_t)idx * S;  c = ws_c[OFF_CNT_Q + idx];
        imp = ws_mut + OFF_IMP_Q + idx;              lgout = out + OUT_QL + (size_t)idx * S;
    } else if (idx < Mq * Wq + Mp * Wp) {
        const int r = idx - Mq * Wq;
        wsum = ws_c + OFF_WSUM_P + (size_t)r * S;    c = ws_c[OFF_CNT_P + r];
        imp = ws_mut + OFF_IMP_P + r;                lgout = out + OUT_PL + (size_t)r * S;
    } else {
        const int r = idx - Mq * Wq - Mp * Wp;
        wsum = ws_c + OFF_WSUM_N + (size_t)r * S;    c = ws_c[OFF_CNT_N + r];
        imp = ws_mut + OFF_IMP_N + r;                lgout = nullptr;
    }

    const bool valid = (c > 0.5f);
    const float inv = valid ? 1.0f / c : 0.0f;

    float lg[S];
#pragma unroll
    for (int s = 0; s < S; ++s)
        lg[s] = valid ? (wsum[s] * inv + pb[s]) : 0.0f;

    float mx = lg[0];
#pragma unroll
    for (int s = 1; s < S; ++s) mx = fmaxf(mx, lg[s]);
    float sum = 0.f, acc = 0.f;
#pragma unroll
    for (int s = 0; s < S; ++s) {
        float e = expf(lg[s] - mx);
        sum += e;
        acc += e * simp[s];
    }
    *imp = valid ? (acc / sum) : NEG_BIG;

    if (lgout) {
#pragma unroll
        for (int s = 0; s < S; ++s) lgout[s] = lg[s];
    }
}

// ---------------------------------------------------------------------------
// Kernel 2b: per-sample softmax over word importance -> per-token coef.
// One block per sample (144 blocks). coef[m][l] = wgt[id[l]] / cnt[id[l]].
// ---------------------------------------------------------------------------
__global__ __launch_bounds__(256) void k_coef(
    const int* __restrict__ q_ids, const int* __restrict__ p_ids,
    const int* __restrict__ n_ids, float* __restrict__ ws)
{
    __shared__ float s_red[256];
    __shared__ float s_wgt[Wp];

    const int by  = blockIdx.x;
    const int tid = threadIdx.x;

    const int* ids; const float* impm; const float* cntm; int L, W;
    if (by < Mq)           { int m = by;
        ids = q_ids + m * Lq; impm = ws + OFF_IMP_Q + m * Wq;
        cntm = ws + OFF_CNT_Q + m * Wq; L = Lq; W = Wq; }
    else if (by < Mq + Mp) { int m = by - Mq;
        ids = p_ids + m * Lp; impm = ws + OFF_IMP_P + m * Wp;
        cntm = ws + OFF_CNT_P + m * Wp; L = Lp; W = Wp; }
    else                   { int m = by - Mq - Mp;
        ids = n_ids + m * Lp; impm = ws + OFF_IMP_N + m * Wp;
        cntm = ws + OFF_CNT_N + m * Wp; L = Lp; W = Wp; }
    float* coef = ws + OFF_COEF + (size_t)by * 512;

    float lm = -FLT_MAX;
    for (int w = tid; w < W; w += 256) lm = fmaxf(lm, impm[w]);
    s_red[tid] = lm;
    __syncthreads();
    for (int st = 128; st > 0; st >>= 1) {
        if (tid < st) s_red[tid] = fmaxf(s_red[tid], s_red[tid + st]);
        __syncthreads();
    }
    const float mx = s_red[0];
    __syncthreads();

    float ls = 0.f;
    for (int w = tid; w < W; w += 256) {
        float e = expf(impm[w] - mx);   // NEG_BIG -> exactly 0
        s_wgt[w] = e;
        ls += e;
    }
    s_red[tid] = ls;
    __syncthreads();
    for (int st = 128; st > 0; st >>= 1) {
        if (tid < st) s_red[tid] += s_red[tid + st];
        __syncthreads();
    }
    const float inv = 1.0f / s_red[0];
    for (int w = tid; w < W; w += 256) s_wgt[w] *= inv;
    __syncthreads();

    for (int l = tid; l < L; l += 256) {
        const int id = ids[l];
        coef[l] = s_wgt[id] / cntm[id];
    }
}

// ---------------------------------------------------------------------------
// Kernel 3: pooled[m,d] = sum_l coef[m,l] * hidden[m,l,d].
// 192 threads, each owns 4 dims (float4); 64-token chunks -> 1088 blocks;
// register accumulate, 4 atomicAdds into zeroed output.
// ---------------------------------------------------------------------------
__global__ __launch_bounds__(192) void k_pool(
    const float* __restrict__ q_h, const float* __restrict__ p_h,
    const float* __restrict__ n_h, const float* __restrict__ ws,
    float* __restrict__ out)
{
    __shared__ float s_c[64];

    const int bx  = blockIdx.x;
    const int tid = threadIdx.x;

    const float* h; float* outp; int L, m, t0, cby;
    if (bx < 64)       { m = bx >> 2;  t0 = (bx & 3) * 64;
        h = q_h; outp = out + OUT_QP + (size_t)m * D; L = Lq; cby = m; }
    else if (bx < 192) { int r = bx - 64;  m = r >> 3;  t0 = (r & 7) * 64;
        h = p_h; outp = out + OUT_PP + (size_t)m * D; L = Lp; cby = Mq + m; }
    else               { int r = bx - 192; m = r >> 3;  t0 = (r & 7) * 64;
        h = n_h; outp = out + OUT_NP + (size_t)m * D; L = Lp; cby = Mq + Mp + m; }

    if (tid < 64) s_c[tid] = ws[OFF_COEF + (size_t)cby * 512 + t0 + tid];
    __syncthreads();

    const float* hb = h + (size_t)m * L * D + (size_t)t0 * D + 4 * tid;

    float4 acc = make_float4(0.f, 0.f, 0.f, 0.f);
#pragma unroll 8
    for (int l = 0; l < 64; ++l) {
        const float4 hv = *(const float4*)(hb + (size_t)l * D);
        const float c = s_c[l];
        acc.x = fmaf(c, hv.x, acc.x);
        acc.y = fmaf(c, hv.y, acc.y);
        acc.z = fmaf(c, hv.z, acc.z);
        acc.w = fmaf(c, hv.w, acc.w);
    }

    float* op = outp + 4 * tid;
    atomicAdd(op + 0, acc.x);
    atomicAdd(op + 1, acc.y);
    atomicAdd(op + 2, acc.z);
    atomicAdd(op + 3, acc.w);
}

// ---------------------------------------------------------------------------
extern "C" void kernel_launch(void* const* d_in, const int* in_sizes, int n_in,
                              void* d_out, int out_size, void* d_ws, size_t ws_size,
                              hipStream_t stream)
{
    const float* q_hidden   = (const float*)d_in[0];
    const float* pos_hidden = (const float*)d_in[1];
    const float* neg_hidden = (const float*)d_in[2];
    const float* proj_w     = (const float*)d_in[3];
    const float* proj_b     = (const float*)d_in[4];
    const float* simp       = (const float*)d_in[5];
    const int*   q_ids      = (const int*)d_in[6];
    const int*   p_ids      = (const int*)d_in[7];
    const int*   n_ids      = (const int*)d_in[8];
    float* out = (float*)d_out;
    float* ws  = (float*)d_ws;

    // zero accumulation regions: workspace (wsum+cnt) and pooled outputs
    hipMemsetAsync(d_ws, 0, (size_t)WS_ZERO_FLOATS * sizeof(float), stream);
    hipMemsetAsync(out, 0, (size_t)24576 * sizeof(float), stream);               // q+p pooled
    hipMemsetAsync(out + OUT_NP, 0, (size_t)(Mn * D) * sizeof(float), stream);   // n pooled

    // proj+accum: 128 (q) + 256 (p) + 1792 (n) = 2176 blocks x 192 threads
    k_proj_accum<<<dim3(2176), dim3(192), 0, stream>>>(
        q_hidden, pos_hidden, neg_hidden, q_ids, p_ids, n_ids, proj_w, ws);

    // finalize: 54400 words
    k_finalize<<<dim3((Mq * Wq + Mp * Wp + Mn * Wp + 255) / 256), dim3(256), 0, stream>>>(
        ws, ws, proj_b, simp, out);

    // per-sample coefficients: 144 blocks
    k_coef<<<dim3(Mq + Mp + Mn), dim3(256), 0, stream>>>(q_ids, p_ids, n_ids, ws);

    // pool: 64 (q) + 128 (p) + 896 (n) = 1088 blocks x 192 threads
    k_pool<<<dim3(1088), dim3(192), 0, stream>>>(
        q_hidden, pos_hidden, neg_hidden, ws, out);
}

// Round 5
// 355.032 us; speedup vs baseline: 1.0072x; 1.0072x over previous
//
#include <hip/hip_runtime.h>
#include <cfloat>

#define NEG_BIG (-1e4f)

constexpr int D = 768;
constexpr int S = 12;

// problem sizes
constexpr int Lq = 256, Lp = 512, Wq = 200, Wp = 400;
constexpr int Mq = 16, Mp = 16, Mn = 112;   // Mn = B*N

// workspace layout (float offsets)
constexpr int OFF_WSUM_Q = 0;                       // 16*200*12  = 38400
constexpr int OFF_WSUM_P = 38400;                   // 16*400*12  = 76800
constexpr int OFF_WSUM_N = 115200;                  // 112*400*12 = 537600
constexpr int OFF_CNT_Q  = 652800;                  // 3200
constexpr int OFF_CNT_P  = 656000;                  // 6400
constexpr int OFF_CNT_N  = 662400;                  // 44800
constexpr int OFF_IMP_Q  = 707200;                  // 3200
constexpr int OFF_IMP_P  = 710400;                  // 6400
constexpr int OFF_IMP_N  = 716800;                  // 44800
constexpr int OFF_COEF   = 761600;                  // 144*512 = 73728 -> 835328 total
constexpr int WS_ZERO_FLOATS = 707200;              // wsum + cnt regions

// output layout (float offsets, reference return order)
constexpr int OUT_QP = 0;        // 16*768
constexpr int OUT_PP = 12288;    // 16*768
constexpr int OUT_QL = 24576;    // 16*200*12
constexpr int OUT_PL = 62976;    // 16*400*12
constexpr int OUT_NP = 139776;   // 112*768 -> 225792 total

// ---------------------------------------------------------------------------
// Kernel 1: per-token projection + segment accumulation.
// 192 threads = 3 waves; wave wv owns dim slice [256*wv, 256*wv+256),
// lane owns 4 dims -> weight cache = 48 VGPRs.
// Round-4 post-mortem: compiler chose VGPR_Count=40 and REMATERIALIZED the
// weight cache as in-loop loads (latency grinder: VALUBusy 29%, 1.1 TB/s).
// Fix: __launch_bounds__(192,2) lifts the VGPR cap, and an opaque inline-asm
// "+v" pin after the load makes rematerialization impossible.
// ---------------------------------------------------------------------------
__global__ __launch_bounds__(192, 2) void k_proj_accum(
    const float* __restrict__ q_h, const float* __restrict__ p_h,
    const float* __restrict__ n_h, const int* __restrict__ q_ids,
    const int* __restrict__ p_ids, const int* __restrict__ n_ids,
    const float* __restrict__ pw, float* __restrict__ ws)
{
    const int bx   = blockIdx.x;
    const int lane = threadIdx.x & 63;
    const int wv   = threadIdx.x >> 6;   // wave id 0..2 = dim slice

    const float* h; const int* ids; float* wsum; float* cnt;
    int L, W, m, t0;
    if (bx < 128)      { h = q_h; ids = q_ids; wsum = ws + OFF_WSUM_Q; cnt = ws + OFF_CNT_Q;
                         L = Lq; W = Wq; m = bx >> 3;  t0 = (bx & 7) * 32; }
    else if (bx < 384) { int r = bx - 128;
                         h = p_h; ids = p_ids; wsum = ws + OFF_WSUM_P; cnt = ws + OFF_CNT_P;
                         L = Lp; W = Wp; m = r >> 4;  t0 = (r & 15) * 32; }
    else               { int r = bx - 384;
                         h = n_h; ids = n_ids; wsum = ws + OFF_WSUM_N; cnt = ws + OFF_CNT_N;
                         L = Lp; W = Wp; m = r >> 4;  t0 = (r & 15) * 32; }

    // register cache of proj_w for this lane's 4 dims (48 floats = 12 float4)
    const int d0 = 256 * wv + 4 * lane;
    float wreg[4][S];
    {
        const float4* base = (const float4*)(pw + (size_t)d0 * S);
#pragma unroll
        for (int q = 0; q < 12; ++q) {
            float4 v = base[q];
            float tmp[4] = {v.x, v.y, v.z, v.w};
#pragma unroll
            for (int c = 0; c < 4; ++c) {
                const int li = 4 * q + c;
                wreg[li / 12][li % 12] = tmp[c];
            }
        }
    }
    // pin the weight cache into VGPRs: opaque to the compiler, so it cannot
    // rematerialize these values from memory inside the token loop.
#pragma unroll
    for (int j = 0; j < 4; ++j)
#pragma unroll
        for (int s = 0; s < S; ++s)
            asm volatile("" : "+v"(wreg[j][s]));

    const float* hbase = h + (size_t)m * L * D + d0;
    const int*   idrow = ids + m * L;

    const bool b5 = lane & 32, b4 = lane & 16, b3 = lane & 8, b2 = lane & 4;
    const int  off_s = b3 ? 2 : (b2 ? 1 : 0);
    const int  s_fin = (b5 ? 6 : 0) + (b4 ? 3 : 0) + off_s;
    const bool do_at = ((lane & 3) == 0) && !(b3 && b2);

#pragma unroll 4
    for (int t = t0; t < t0 + 32; ++t) {
        const int id = idrow[t];
        const float4 hv = *(const float4*)(hbase + (size_t)t * D);

        float p[S];
        {
            const float hj[4] = {hv.x, hv.y, hv.z, hv.w};
#pragma unroll
            for (int s = 0; s < S; ++s) p[s] = hj[0] * wreg[0][s];
#pragma unroll
            for (int j = 1; j < 4; ++j)
#pragma unroll
                for (int s = 0; s < S; ++s)
                    p[s] = fmaf(hj[j], wreg[j][s], p[s]);
        }

        // ---- redistribution reduce: 12 vals over 64 lanes, 14 swizzles ----
        float a[6];
#pragma unroll
        for (int i = 0; i < 6; ++i) {
            float snd = b5 ? p[i] : p[6 + i];
            float kp  = b5 ? p[6 + i] : p[i];
            a[i] = kp + __shfl_xor(snd, 32, 64);
        }
        float b[3];
#pragma unroll
        for (int i = 0; i < 3; ++i) {
            float snd = b4 ? a[i] : a[3 + i];
            float kp  = b4 ? a[3 + i] : a[i];
            b[i] = kp + __shfl_xor(snd, 16, 64);
        }
        float c0, c1;
        {
            float snd0 = b3 ? b[0] : b[2];
            float kp0  = b3 ? b[2] : b[0];
            c0 = kp0 + __shfl_xor(snd0, 8, 64);
            float snd1 = b3 ? b[1] : 0.f;
            float kp1  = b3 ? 0.f  : b[1];
            c1 = kp1 + __shfl_xor(snd1, 8, 64);
        }
        float snd = b3 ? c0 : (b2 ? c0 : c1);
        float kp  = b3 ? c0 : (b2 ? c1 : c0);
        float d   = kp + __shfl_xor(snd, 4, 64);
        d += __shfl_xor(d, 2, 64);
        d += __shfl_xor(d, 1, 64);

        float* wb = wsum + ((size_t)m * W + id) * S;
        if (do_at)                atomicAdd(wb + s_fin, d);
        if (wv == 0 && lane == 1) atomicAdd(cnt + (size_t)m * W + id, 1.0f);
    }
}

// ---------------------------------------------------------------------------
// Kernel 2: per-word mean + bias, mask, softmax over S, importance.
// ---------------------------------------------------------------------------
__global__ void k_finalize(
    const float* __restrict__ ws_c, float* __restrict__ ws_mut,
    const float* __restrict__ pb, const float* __restrict__ simp,
    float* __restrict__ out)
{
    const int idx = blockIdx.x * blockDim.x + threadIdx.x;
    if (idx >= Mq * Wq + Mp * Wp + Mn * Wp) return;

    const float* wsum; float c; float* imp; float* lgout;
    if (idx < Mq * Wq) {
        wsum = ws_c + OFF_WSUM_Q + (size_t)idx * S;  c = ws_c[OFF_CNT_Q + idx];
        imp = ws_mut + OFF_IMP_Q + idx;              lgout = out + OUT_QL + (size_t)idx * S;
    } else if (idx < Mq * Wq + Mp * Wp) {
        const int r = idx - Mq * Wq;
        wsum = ws_c + OFF_WSUM_P + (size_t)r * S;    c = ws_c[OFF_CNT_P + r];
        imp = ws_mut + OFF_IMP_P + r;                lgout = out + OUT_PL + (size_t)r * S;
    } else {
        const int r = idx - Mq * Wq - Mp * Wp;
        wsum = ws_c + OFF_WSUM_N + (size_t)r * S;    c = ws_c[OFF_CNT_N + r];
        imp = ws_mut + OFF_IMP_N + r;                lgout = nullptr;
    }

    const bool valid = (c > 0.5f);
    const float inv = valid ? 1.0f / c : 0.0f;

    float lg[S];
#pragma unroll
    for (int s = 0; s < S; ++s)
        lg[s] = valid ? (wsum[s] * inv + pb[s]) : 0.0f;

    float mx = lg[0];
#pragma unroll
    for (int s = 1; s < S; ++s) mx = fmaxf(mx, lg[s]);
    float sum = 0.f, acc = 0.f;
#pragma unroll
    for (int s = 0; s < S; ++s) {
        float e = expf(lg[s] - mx);
        sum += e;
        acc += e * simp[s];
    }
    *imp = valid ? (acc / sum) : NEG_BIG;

    if (lgout) {
#pragma unroll
        for (int s = 0; s < S; ++s) lgout[s] = lg[s];
    }
}

// ---------------------------------------------------------------------------
// Kernel 2b: per-sample softmax over word importance -> per-token coef.
// One block per sample (144 blocks). coef[m][l] = wgt[id[l]] / cnt[id[l]].
// ---------------------------------------------------------------------------
__global__ __launch_bounds__(256) void k_coef(
    const int* __restrict__ q_ids, const int* __restrict__ p_ids,
    const int* __restrict__ n_ids, float* __restrict__ ws)
{
    __shared__ float s_red[256];
    __shared__ float s_wgt[Wp];

    const int by  = blockIdx.x;
    const int tid = threadIdx.x;

    const int* ids; const float* impm; const float* cntm; int L, W;
    if (by < Mq)           { int m = by;
        ids = q_ids + m * Lq; impm = ws + OFF_IMP_Q + m * Wq;
        cntm = ws + OFF_CNT_Q + m * Wq; L = Lq; W = Wq; }
    else if (by < Mq + Mp) { int m = by - Mq;
        ids = p_ids + m * Lp; impm = ws + OFF_IMP_P + m * Wp;
        cntm = ws + OFF_CNT_P + m * Wp; L = Lp; W = Wp; }
    else                   { int m = by - Mq - Mp;
        ids = n_ids + m * Lp; impm = ws + OFF_IMP_N + m * Wp;
        cntm = ws + OFF_CNT_N + m * Wp; L = Lp; W = Wp; }
    float* coef = ws + OFF_COEF + (size_t)by * 512;

    float lm = -FLT_MAX;
    for (int w = tid; w < W; w += 256) lm = fmaxf(lm, impm[w]);
    s_red[tid] = lm;
    __syncthreads();
    for (int st = 128; st > 0; st >>= 1) {
        if (tid < st) s_red[tid] = fmaxf(s_red[tid], s_red[tid + st]);
        __syncthreads();
    }
    const float mx = s_red[0];
    __syncthreads();

    float ls = 0.f;
    for (int w = tid; w < W; w += 256) {
        float e = expf(impm[w] - mx);   // NEG_BIG -> exactly 0
        s_wgt[w] = e;
        ls += e;
    }
    s_red[tid] = ls;
    __syncthreads();
    for (int st = 128; st > 0; st >>= 1) {
        if (tid < st) s_red[tid] += s_red[tid + st];
        __syncthreads();
    }
    const float inv = 1.0f / s_red[0];
    for (int w = tid; w < W; w += 256) s_wgt[w] *= inv;
    __syncthreads();

    for (int l = tid; l < L; l += 256) {
        const int id = ids[l];
        coef[l] = s_wgt[id] / cntm[id];
    }
}

// ---------------------------------------------------------------------------
// Kernel 3: pooled[m,d] = sum_l coef[m,l] * hidden[m,l,d].
// 192 threads, each owns 4 dims (float4); 64-token chunks -> 1088 blocks;
// register accumulate, 4 atomicAdds into zeroed output.
// (Deliberately unchanged from round 4 for clean attribution of the
//  k_proj_accum fix.)
// ---------------------------------------------------------------------------
__global__ __launch_bounds__(192) void k_pool(
    const float* __restrict__ q_h, const float* __restrict__ p_h,
    const float* __restrict__ n_h, const float* __restrict__ ws,
    float* __restrict__ out)
{
    __shared__ float s_c[64];

    const int bx  = blockIdx.x;
    const int tid = threadIdx.x;

    const float* h; float* outp; int L, m, t0, cby;
    if (bx < 64)       { m = bx >> 2;  t0 = (bx & 3) * 64;
        h = q_h; outp = out + OUT_QP + (size_t)m * D; L = Lq; cby = m; }
    else if (bx < 192) { int r = bx - 64;  m = r >> 3;  t0 = (r & 7) * 64;
        h = p_h; outp = out + OUT_PP + (size_t)m * D; L = Lp; cby = Mq + m; }
    else               { int r = bx - 192; m = r >> 3;  t0 = (r & 7) * 64;
        h = n_h; outp = out + OUT_NP + (size_t)m * D; L = Lp; cby = Mq + Mp + m; }

    if (tid < 64) s_c[tid] = ws[OFF_COEF + (size_t)cby * 512 + t0 + tid];
    __syncthreads();

    const float* hb = h + (size_t)m * L * D + (size_t)t0 * D + 4 * tid;

    float4 acc = make_float4(0.f, 0.f, 0.f, 0.f);
#pragma unroll 8
    for (int l = 0; l < 64; ++l) {
        const float4 hv = *(const float4*)(hb + (size_t)l * D);
        const float c = s_c[l];
        acc.x = fmaf(c, hv.x, acc.x);
        acc.y = fmaf(c, hv.y, acc.y);
        acc.z = fmaf(c, hv.z, acc.z);
        acc.w = fmaf(c, hv.w, acc.w);
    }

    float* op = outp + 4 * tid;
    atomicAdd(op + 0, acc.x);
    atomicAdd(op + 1, acc.y);
    atomicAdd(op + 2, acc.z);
    atomicAdd(op + 3, acc.w);
}

// ---------------------------------------------------------------------------
extern "C" void kernel_launch(void* const* d_in, const int* in_sizes, int n_in,
                              void* d_out, int out_size, void* d_ws, size_t ws_size,
                              hipStream_t stream)
{
    const float* q_hidden   = (const float*)d_in[0];
    const float* pos_hidden = (const float*)d_in[1];
    const float* neg_hidden = (const float*)d_in[2];
    const float* proj_w     = (const float*)d_in[3];
    const float* proj_b     = (const float*)d_in[4];
    const float* simp       = (const float*)d_in[5];
    const int*   q_ids      = (const int*)d_in[6];
    const int*   p_ids      = (const int*)d_in[7];
    const int*   n_ids      = (const int*)d_in[8];
    float* out = (float*)d_out;
    float* ws  = (float*)d_ws;

    // zero accumulation regions: workspace (wsum+cnt) and pooled outputs
    hipMemsetAsync(d_ws, 0, (size_t)WS_ZERO_FLOATS * sizeof(float), stream);
    hipMemsetAsync(out, 0, (size_t)24576 * sizeof(float), stream);               // q+p pooled
    hipMemsetAsync(out + OUT_NP, 0, (size_t)(Mn * D) * sizeof(float), stream);   // n pooled

    // proj+accum: 128 (q) + 256 (p) + 1792 (n) = 2176 blocks x 192 threads
    k_proj_accum<<<dim3(2176), dim3(192), 0, stream>>>(
        q_hidden, pos_hidden, neg_hidden, q_ids, p_ids, n_ids, proj_w, ws);

    // finalize: 54400 words
    k_finalize<<<dim3((Mq * Wq + Mp * Wp + Mn * Wp + 255) / 256), dim3(256), 0, stream>>>(
        ws, ws, proj_b, simp, out);

    // per-sample coefficients: 144 blocks
    k_coef<<<dim3(Mq + Mp + Mn), dim3(256), 0, stream>>>(q_ids, p_ids, n_ids, ws);

    // pool: 64 (q) + 128 (p) + 896 (n) = 1088 blocks x 192 threads
    k_pool<<<dim3(1088), dim3(192), 0, stream>>>(
        q_hidden, pos_hidden, neg_hidden, ws, out);
}